// Round 4
// baseline (458.191 us; speedup 1.0000x reference)
//
#include <hip/hip_runtime.h>

// VQ-VAE VectorQuantizer: x[32768,256] fp32, emb[256,1024] fp32.
// Round 4: bf16-MFMA screen + exact-fp32-chain rescue.
//   screen: dist^ = A - 2*(xh.eh) + C via mfma_f32_16x16x32_bf16; store per-row
//           per-16-code group mins (gmin16[32768][64]).
//   rescue: groups with gmin <= min + margin get the EXACT reference chain
//           (sequential-d fmaf, fl(fl(A-2B)+C)) — bit-identical to the
//           round-2/3 passing kernel; first-index argmin semantics preserved.
//   margin soundness: |screen-chain| <= 2*(2^-9+2^-9+2^-18)*Sabs*emax + slop.

#define D 256
#define K 1024
#define N_PTS 32768

typedef __attribute__((ext_vector_type(8))) short short8v;   // 8 bf16 (4 VGPR)
typedef __attribute__((ext_vector_type(4))) float f32x4;     // MFMA acc
typedef __attribute__((ext_vector_type(4))) unsigned short us4v;

__device__ __forceinline__ unsigned short bf16rne(float f) {
    unsigned u = __float_as_uint(f);                 // finite data, no NaN
    return (unsigned short)((u + 0x7FFFu + ((u >> 16) & 1u)) >> 16);
}

// ws layout (bytes):
//   0        float  enorm[1024]        4 KB   (numpy-sequential fp32 ||e||^2)
//   8192     double lossacc            8 B
//   16384    float  Anorm[32768]       128 KB (numpy pairwise ||x||^2)
//   147456   float  Sabs[32768]        128 KB (sum|x| for margin bound)
//   278528   int    bestidx[32768]     128 KB
//   409600   ushort ehT[1024][256]     512 KB (bf16, code-major)
//   933888   float  embT[1024][256]    1 MB   (f32, for merge gather)
//   1982464  float  gmin16[32768][64]  8 MB
// xh bf16 [32768][256] (16 MB) lives in d_out scratch (overwritten by merge).

__global__ __launch_bounds__(256) void vq_prepx(const float* __restrict__ x,
                                                float* __restrict__ Anorm,
                                                float* __restrict__ Sabs,
                                                unsigned short* __restrict__ xh) {
    const int tid = threadIdx.x;
    const int gt  = blockIdx.x * 256 + tid;
    const int n   = gt >> 1;
    const int h   = gt & 1;            // lane pair (2j,2j+1) = halves of row n
    const float4* __restrict__ xr =
        reinterpret_cast<const float4*>(x + (size_t)n * D) + h * 32;
    unsigned short* __restrict__ xo = xh + (size_t)n * D + h * 128;

    // numpy pairwise fp32 half-block: 8 accumulators, strided adds,
    // combine ((r0+r1)+(r2+r3))+((r4+r5)+(r6+r7))  (identical to r3 vq_anorm)
    float r[8], sab;
    float4 u = xr[0], v = xr[1];
    {
        short8v p;
        p[0]=(short)bf16rne(u.x); p[1]=(short)bf16rne(u.y);
        p[2]=(short)bf16rne(u.z); p[3]=(short)bf16rne(u.w);
        p[4]=(short)bf16rne(v.x); p[5]=(short)bf16rne(v.y);
        p[6]=(short)bf16rne(v.z); p[7]=(short)bf16rne(v.w);
        *reinterpret_cast<short8v*>(xo) = p;
    }
    r[0]=__fmul_rn(u.x,u.x); r[1]=__fmul_rn(u.y,u.y);
    r[2]=__fmul_rn(u.z,u.z); r[3]=__fmul_rn(u.w,u.w);
    r[4]=__fmul_rn(v.x,v.x); r[5]=__fmul_rn(v.y,v.y);
    r[6]=__fmul_rn(v.z,v.z); r[7]=__fmul_rn(v.w,v.w);
    sab = fabsf(u.x)+fabsf(u.y)+fabsf(u.z)+fabsf(u.w)
        + fabsf(v.x)+fabsf(v.y)+fabsf(v.z)+fabsf(v.w);
    #pragma unroll
    for (int i = 1; i < 16; ++i) {
        u = xr[2*i]; v = xr[2*i+1];
        short8v p;
        p[0]=(short)bf16rne(u.x); p[1]=(short)bf16rne(u.y);
        p[2]=(short)bf16rne(u.z); p[3]=(short)bf16rne(u.w);
        p[4]=(short)bf16rne(v.x); p[5]=(short)bf16rne(v.y);
        p[6]=(short)bf16rne(v.z); p[7]=(short)bf16rne(v.w);
        *reinterpret_cast<short8v*>(xo + i * 8) = p;
        r[0]=__fadd_rn(r[0],__fmul_rn(u.x,u.x));
        r[1]=__fadd_rn(r[1],__fmul_rn(u.y,u.y));
        r[2]=__fadd_rn(r[2],__fmul_rn(u.z,u.z));
        r[3]=__fadd_rn(r[3],__fmul_rn(u.w,u.w));
        r[4]=__fadd_rn(r[4],__fmul_rn(v.x,v.x));
        r[5]=__fadd_rn(r[5],__fmul_rn(v.y,v.y));
        r[6]=__fadd_rn(r[6],__fmul_rn(v.z,v.z));
        r[7]=__fadd_rn(r[7],__fmul_rn(v.w,v.w));
        sab += fabsf(u.x)+fabsf(u.y)+fabsf(u.z)+fabsf(u.w)
             + fabsf(v.x)+fabsf(v.y)+fabsf(v.z)+fabsf(v.w);
    }
    float ah = __fadd_rn(__fadd_rn(__fadd_rn(r[0],r[1]),__fadd_rn(r[2],r[3])),
                         __fadd_rn(__fadd_rn(r[4],r[5]),__fadd_rn(r[6],r[7])));
    float oh = __shfl_xor(ah, 1);
    float os = __shfl_xor(sab, 1);
    if (h == 0) {
        Anorm[n] = __fadd_rn(ah, oh);   // fl(half0 + half1), numpy order
        Sabs[n]  = sab + os;
    }
}

__global__ __launch_bounds__(256) void vq_enorm(const float* __restrict__ emb,
                                                float* __restrict__ enorm) {
    int k = blockIdx.x * 256 + threadIdx.x;
    float c = 0.0f;   // numpy axis-0 sum: sequential over d, square rounded first
    for (int d = 0; d < D; ++d) {
        float e = emb[d * K + k];
        c = __fadd_rn(c, __fmul_rn(e, e));
    }
    enorm[k] = c;
}

// emb transpose: embT[k][d] f32 (merge gather) + ehT[k][d] bf16 (screen B)
__global__ __launch_bounds__(256) void vq_prepe(const float* __restrict__ emb,
                                                float* __restrict__ embT,
                                                unsigned short* __restrict__ ehT) {
    __shared__ float tile[64][68];
    const int bk = blockIdx.x >> 2, bd = blockIdx.x & 3;
    const int k0 = bk * 64, d0 = bd * 64;
    const int t = threadIdx.x;
    #pragma unroll
    for (int s = 0; s < 4; ++s) {
        int li = s * 256 + t;
        int dd = li >> 4, kq = li & 15;
        float4 v = *reinterpret_cast<const float4*>(&emb[(size_t)(d0 + dd) * K + k0 + kq * 4]);
        tile[dd][kq*4+0]=v.x; tile[dd][kq*4+1]=v.y;
        tile[dd][kq*4+2]=v.z; tile[dd][kq*4+3]=v.w;
    }
    __syncthreads();
    #pragma unroll
    for (int s = 0; s < 4; ++s) {
        int li = s * 256 + t;
        int kk = li >> 4, dq = li & 15;
        float4 v;
        v.x = tile[dq*4+0][kk]; v.y = tile[dq*4+1][kk];
        v.z = tile[dq*4+2][kk]; v.w = tile[dq*4+3][kk];
        *reinterpret_cast<float4*>(&embT[(size_t)(k0+kk)*D + d0 + dq*4]) = v;
        us4v hq;
        hq[0]=bf16rne(v.x); hq[1]=bf16rne(v.y); hq[2]=bf16rne(v.z); hq[3]=bf16rne(v.w);
        *reinterpret_cast<us4v*>(&ehT[(size_t)(k0+kk)*D + d0 + dq*4]) = hq;
    }
}

// ---- bf16 MFMA screen: 128x128 tile, 4 waves (2x2), 16x16x32 MFMA ----
#define LDSTR 40   // ushorts per LDS row (80B): 16B-aligned, 2-way banks (free)

__global__ __launch_bounds__(256) void vq_screen(const unsigned short* __restrict__ xh,
                                                 const unsigned short* __restrict__ ehT,
                                                 const float* __restrict__ Anorm,
                                                 const float* __restrict__ enorm,
                                                 float* __restrict__ gmin16) {
    __shared__ unsigned short a_lds[128 * LDSTR];
    __shared__ unsigned short b_lds[128 * LDSTR];
    const int tid = threadIdx.x;
    const int l = tid & 63, wid = tid >> 6;
    const int wr = wid >> 1, wc = wid & 1;        // wave tile 64x64
    const int rt = blockIdx.x >> 3, cc = blockIdx.x & 7;
    const int n0 = rt * 128, c0 = cc * 128;
    const int g = l >> 4, cl = l & 15;

    f32x4 acc[4][4];
    #pragma unroll
    for (int mf = 0; mf < 4; ++mf)
        #pragma unroll
        for (int nf = 0; nf < 4; ++nf)
            acc[mf][nf] = (f32x4){0.f, 0.f, 0.f, 0.f};

    const int srow = tid >> 1, sq = (tid & 1) * 2;   // staging: 2x16B per thread
    for (int s = 0; s < 8; ++s) {                    // K = 8 steps of 32
        __syncthreads();
        {
            const short8v* ga = reinterpret_cast<const short8v*>(
                xh + (size_t)(n0 + srow) * D + s * 32 + sq * 8);
            short8v a0 = ga[0], a1 = ga[1];
            *reinterpret_cast<short8v*>(&a_lds[srow * LDSTR + sq * 8])     = a0;
            *reinterpret_cast<short8v*>(&a_lds[srow * LDSTR + sq * 8 + 8]) = a1;
            const short8v* gb = reinterpret_cast<const short8v*>(
                ehT + (size_t)(c0 + srow) * D + s * 32 + sq * 8);
            short8v b0 = gb[0], b1 = gb[1];
            *reinterpret_cast<short8v*>(&b_lds[srow * LDSTR + sq * 8])     = b0;
            *reinterpret_cast<short8v*>(&b_lds[srow * LDSTR + sq * 8 + 8]) = b1;
        }
        __syncthreads();
        short8v af[4], bf[4];
        #pragma unroll
        for (int mf = 0; mf < 4; ++mf)
            af[mf] = *reinterpret_cast<const short8v*>(
                &a_lds[(wr * 64 + mf * 16 + cl) * LDSTR + g * 8]);
        #pragma unroll
        for (int nf = 0; nf < 4; ++nf)
            bf[nf] = *reinterpret_cast<const short8v*>(
                &b_lds[(wc * 64 + nf * 16 + cl) * LDSTR + g * 8]);
        // consistent (g,j)->k mapping on A and B => correct GEMM regardless of
        // HW k-slot order; C/D layout: col=lane&15, row=(lane>>4)*4+reg (m89)
        #pragma unroll
        for (int mf = 0; mf < 4; ++mf)
            #pragma unroll
            for (int nf = 0; nf < 4; ++nf)
                acc[mf][nf] = __builtin_amdgcn_mfma_f32_16x16x32_bf16(
                    af[mf], bf[nf], acc[mf][nf], 0, 0, 0);
    }

    // epilogue: screen dist + per-row 16-code group mins
    #pragma unroll
    for (int mf = 0; mf < 4; ++mf) {
        #pragma unroll
        for (int nf = 0; nf < 4; ++nf) {
            f32x4 a = acc[mf][nf];
            const int cg = c0 + wc * 64 + nf * 16 + cl;
            const float C = enorm[cg];
            #pragma unroll
            for (int r = 0; r < 4; ++r) {
                const int ng = n0 + wr * 64 + mf * 16 + g * 4 + r;
                float dist = Anorm[ng] - 2.0f * a[r] + C;   // approx, self-consistent
                #pragma unroll
                for (int m = 1; m <= 8; m <<= 1)
                    dist = fminf(dist, __shfl_xor(dist, m));
                if (cl == 0)
                    gmin16[(size_t)ng * 64 + cc * 8 + wc * 4 + nf] = dist;
            }
        }
    }
}

// ---- exact rescue: flagged groups get the reference fp32 chain ----
__global__ __launch_bounds__(256) void vq_rescue(const float* __restrict__ x,
                                                 const float* __restrict__ emb,
                                                 const float* __restrict__ Anorm,
                                                 const float* __restrict__ Sabs,
                                                 const float* __restrict__ enorm,
                                                 const float* __restrict__ gmin16,
                                                 int* __restrict__ bestidx) {
    const int tid = threadIdx.x, l = tid & 63, w = tid >> 6;
    const int row = blockIdx.x * 4 + w;
    float gv = gmin16[(size_t)row * 64 + l];
    float gm = gv;
    #pragma unroll
    for (int m = 1; m < 64; m <<= 1) gm = fminf(gm, __shfl_xor(gm, m));
    // sound |screen-chain| bound: 2*(2^-9+2^-9+2^-18)*Sabs*emax(+slop), doubled
    const float margin = fmaf(Sabs[row] * 0.05f, 0.017f, 0.002f);
    unsigned long long mask = __ballot(gv <= gm + margin);
    const float A = Anorm[row];
    const float4* __restrict__ xr = reinterpret_cast<const float4*>(x + (size_t)row * D);
    float bestd = 1e30f; int besti = 0x7fffffff;
    while (mask) {
        const int gp = __builtin_ctzll(mask);   // ascending groups
        mask &= mask - 1;
        const int k = gp * 16 + (l & 15);       // lanes 16-63 duplicate (harmless)
        float c = 0.f;                          // EXACT reference chain: seq d fmaf
        #pragma unroll 4
        for (int d8 = 0; d8 < 32; ++d8) {
            float4 xa = xr[d8 * 2], xb = xr[d8 * 2 + 1];
            float e0 = emb[(d8*8+0)*K + k], e1 = emb[(d8*8+1)*K + k];
            float e2 = emb[(d8*8+2)*K + k], e3 = emb[(d8*8+3)*K + k];
            float e4 = emb[(d8*8+4)*K + k], e5 = emb[(d8*8+5)*K + k];
            float e6 = emb[(d8*8+6)*K + k], e7 = emb[(d8*8+7)*K + k];
            c = fmaf(xa.x, e0, c); c = fmaf(xa.y, e1, c);
            c = fmaf(xa.z, e2, c); c = fmaf(xa.w, e3, c);
            c = fmaf(xb.x, e4, c); c = fmaf(xb.y, e5, c);
            c = fmaf(xb.z, e6, c); c = fmaf(xb.w, e7, c);
        }
        float dist = __fadd_rn(__fsub_rn(A, 2.0f * c), enorm[k]);  // fl(fl(A-2B)+C)
        if (dist < bestd || (dist == bestd && k < besti)) { bestd = dist; besti = k; }
    }
    #pragma unroll
    for (int m = 1; m < 64; m <<= 1) {          // lexicographic (dist, idx) min
        float od = __shfl_xor(bestd, m);
        int   oi = __shfl_xor(besti, m);
        if (od < bestd || (od == bestd && oi < besti)) { bestd = od; besti = oi; }
    }
    if (l == 0) bestidx[row] = besti;
}

__global__ __launch_bounds__(256) void vq_merge(const float* __restrict__ x,
                                                const float* __restrict__ embT,
                                                const int* __restrict__ bestidx,
                                                float* __restrict__ out,
                                                double* __restrict__ lossacc) {
    const int tid = threadIdx.x;
    const int n  = blockIdx.x * 64 + (tid >> 2);
    const int dq = tid & 3;
    const int bi = bestidx[n];
    const float4* x4 = reinterpret_cast<const float4*>(x + (size_t)n * D);
    const float4* e4 = reinterpret_cast<const float4*>(embT + (size_t)bi * D);
    float4* o4 = reinterpret_cast<float4*>(out + (size_t)n * D);
    double lsum = 0.0;
    #pragma unroll
    for (int i = 0; i < 16; ++i) {
        int idx = i * 4 + dq;
        float4 xv = x4[idx];
        float4 q  = e4[idx];
        o4[idx] = q;                       // exact pass-through of selected code
        double dxx;
        dxx = (double)q.x - (double)xv.x; lsum = fma(dxx, dxx, lsum);
        dxx = (double)q.y - (double)xv.y; lsum = fma(dxx, dxx, lsum);
        dxx = (double)q.z - (double)xv.z; lsum = fma(dxx, dxx, lsum);
        dxx = (double)q.w - (double)xv.w; lsum = fma(dxx, dxx, lsum);
    }
    for (int off = 32; off > 0; off >>= 1) lsum += __shfl_down(lsum, off);
    if ((tid & 63) == 0) atomicAdd(lossacc, lsum);
}

__global__ void vq_loss(const double* __restrict__ lossacc, float* __restrict__ out_loss) {
    if (threadIdx.x == 0 && blockIdx.x == 0) {
        out_loss[0] = (float)(1.25 * (lossacc[0] / (double)((size_t)N_PTS * D)));
    }
}

extern "C" void kernel_launch(void* const* d_in, const int* in_sizes, int n_in,
                              void* d_out, int out_size, void* d_ws, size_t ws_size,
                              hipStream_t stream) {
    const float* x   = (const float*)d_in[0];
    const float* emb = (const float*)d_in[1];
    float* out = (float*)d_out;
    char* ws = (char*)d_ws;

    float*  enorm   = (float*)(ws);
    double* lossacc = (double*)(ws + 8192);
    float*  Anorm   = (float*)(ws + 16384);
    float*  Sabs    = (float*)(ws + 147456);
    int*    bestidx = (int*)(ws + 278528);
    unsigned short* ehT = (unsigned short*)(ws + 409600);
    float*  embT    = (float*)(ws + 933888);
    float*  gmin16  = (float*)(ws + 1982464);           // 8 MB, ends ~10.4 MB
    unsigned short* xh = (unsigned short*)out;          // 16 MB scratch in d_out;
                                                        // merge overwrites later
    hipMemsetAsync(lossacc, 0, sizeof(double), stream);
    vq_prepx<<<N_PTS * 2 / 256, 256, 0, stream>>>(x, Anorm, Sabs, xh);
    vq_enorm<<<K / 256, 256, 0, stream>>>(emb, enorm);
    vq_prepe<<<64, 256, 0, stream>>>(emb, embT, ehT);
    vq_screen<<<(N_PTS / 128) * (K / 128), 256, 0, stream>>>(xh, ehT, Anorm, enorm, gmin16);
    vq_rescue<<<N_PTS / 4, 256, 0, stream>>>(x, emb, Anorm, Sabs, enorm, gmin16, bestidx);
    vq_merge<<<N_PTS / 64, 256, 0, stream>>>(x, embT, bestidx, out, lossacc);
    vq_loss<<<1, 64, 0, stream>>>(lossacc, out + (size_t)N_PTS * D);
}